// Round 2
// 664.962 us; speedup vs baseline: 1.0949x; 1.0949x over previous
//
#include <hip/hip_runtime.h>
#include <math.h>

typedef __attribute__((ext_vector_type(8))) short bf16x8;  // 8 bf16 = 4 VGPR
typedef __attribute__((ext_vector_type(4))) float f32x4;   // MFMA acc

constexpr int LST = 72;    // B-tile LDS row stride (shorts): 144 B
constexpr int AST = 520;   // att1 A-tile LDS row stride (shorts): 1040 B (bank step 4 -> 2-way max)

__device__ __forceinline__ unsigned short f2b(float f) {
    union { float f; unsigned int i; } c; c.f = f;
    unsigned int i = c.i;
    return (unsigned short)((i + 0x7fffu + ((i >> 16) & 1u)) >> 16);  // RNE
}
__device__ __forceinline__ void unpack2(unsigned int v, float& lo, float& hi) {
    union { unsigned int i; float f; } c0, c1;
    c0.i = v << 16; c1.i = v & 0xffff0000u;
    lo = c0.f; hi = c1.f;
}
__device__ __forceinline__ uint2 pack4(float4 v) {
    uint2 pk;
    pk.x = (unsigned int)f2b(v.x) | ((unsigned int)f2b(v.y) << 16);
    pk.y = (unsigned int)f2b(v.z) | ((unsigned int)f2b(v.w) << 16);
    return pk;
}
__device__ __forceinline__ float sigf(float x) { return 1.f / (1.f + __expf(-x)); }
__device__ __forceinline__ float tanhfast(float x) { return 1.f - 2.f / (1.f + __expf(2.f * x)); }

// ---------------- gate GEMM + fused LSTM cell ----------------
// gates = [A-pieces]@[W-pieces]^T + b_ih + b_hh, gate-interleaved N-mapping:
// block covers j0..j0+16 for all 4 gates; lane holds (i,f,g,o) of same (b,j).
template<int NT>
__device__ __forceinline__ void gate_body(
    int bx, int t, unsigned short* Al, unsigned short* Bl,
    const float* __restrict__ A0, const float* __restrict__ A1,
    const float* __restrict__ A2, const float* __restrict__ A3,
    int as0, int as1, int as2, int as3,
    const float* __restrict__ B0, const float* __restrict__ B1,
    const float* __restrict__ B2, const float* __restrict__ B3,
    int bs0, int bs1, int bs2, int bs3,
    const float* __restrict__ b_ih, const float* __restrict__ b_hh,
    const float* __restrict__ c_prev, float* __restrict__ h_out,
    float* __restrict__ c_out, float* __restrict__ h_dup, int K)
{
    constexpr int BM = NT / 4;          // rows per block
    constexpr int MBLK = 512 / BM;
    constexpr int NA = BM * 16 / NT;    // A float4-chunks per thread
    constexpr int NB = 1024 / NT;       // B float4-chunks per thread
    const int mb = bx % MBLK, jb = bx / MBLK;
    const int m0 = mb * BM, j0 = jb * 16;
    const int w = t >> 6, lane = t & 63;
    const int col = lane & 15, hi = lane >> 4;

    f32x4 acc[4];
#pragma unroll
    for (int g = 0; g < 4; ++g)
#pragma unroll
        for (int r = 0; r < 4; ++r) acc[g][r] = 0.f;

    for (int kt = 0; kt < K; kt += 64) {
        const int p = kt >> 9, kin = kt & 511;
        const float* ap = (p == 0) ? A0 : (p == 1) ? A1 : (p == 2) ? A2 : A3;
        const int astr   = (p == 0) ? as0 : (p == 1) ? as1 : (p == 2) ? as2 : as3;
        const float* bp = (p == 0) ? B0 : (p == 1) ? B1 : (p == 2) ? B2 : B3;
        const int bstr   = (p == 0) ? bs0 : (p == 1) ? bs1 : (p == 2) ? bs2 : bs3;
        float4 ta[NA], tb[NB];
#pragma unroll
        for (int k = 0; k < NA; ++k) {
            const int c = t + k * NT, row = c >> 4, q = c & 15;
            ta[k] = *(const float4*)(ap + (astr ? (size_t)(m0 + row) * astr : 0) + kin + q * 4);
        }
#pragma unroll
        for (int k = 0; k < NB; ++k) {
            const int c = t + k * NT, row = c >> 4, q = c & 15;
            const int brow = (row >> 4) * 512 + j0 + (row & 15);
            tb[k] = *(const float4*)(bp + (size_t)brow * bstr + kin + q * 4);
        }
        __syncthreads();   // previous tile's LDS reads done
#pragma unroll
        for (int k = 0; k < NA; ++k) {
            const int c = t + k * NT, row = c >> 4, q = c & 15;
            *(uint2*)&Al[row * LST + q * 4] = pack4(ta[k]);
        }
#pragma unroll
        for (int k = 0; k < NB; ++k) {
            const int c = t + k * NT, row = c >> 4, q = c & 15;
            *(uint2*)&Bl[row * LST + q * 4] = pack4(tb[k]);
        }
        __syncthreads();
#pragma unroll
        for (int sub = 0; sub < 2; ++sub) {
            const int ko = sub * 32 + hi * 8;
            const bf16x8 af = *(const bf16x8*)&Al[(w * 16 + col) * LST + ko];
#pragma unroll
            for (int g = 0; g < 4; ++g) {
                const bf16x8 bfr = *(const bf16x8*)&Bl[(g * 16 + col) * LST + ko];
                acc[g] = __builtin_amdgcn_mfma_f32_16x16x32_bf16(af, bfr, acc[g], 0, 0, 0);
            }
        }
    }
    // epilogue: LSTM cell per lane
    const int j = j0 + col;
    const float bi = b_ih[j]        + b_hh[j];
    const float bf = b_ih[512 + j]  + b_hh[512 + j];
    const float bg = b_ih[1024 + j] + b_hh[1024 + j];
    const float bo = b_ih[1536 + j] + b_hh[1536 + j];
#pragma unroll
    for (int r = 0; r < 4; ++r) {
        const int bidx = m0 + w * 16 + hi * 4 + r;
        const size_t off = (size_t)bidx * 512 + j;
        const float gi = acc[0][r] + bi, gf = acc[1][r] + bf;
        const float gg = acc[2][r] + bg, go = acc[3][r] + bo;
        const float c = c_prev[off];
        const float cn = sigf(gf) * c + sigf(gi) * tanhfast(gg);
        const float hn = sigf(go) * tanhfast(cn);
        h_out[off] = hn;
        c_out[off] = cn;
        if (h_dup) h_dup[off] = hn;
    }
}

// ---------------- att1 v2: 32-row block, whole-K LDS-resident A, mask-skip ----------------
// Phase-1 staging split into two 8-chunk batches: halves peak VGPR liveness
// (16 x float4 = 64 VGPR -> 32) so the kernel fits the 3-waves/EU budget.
__device__ __forceinline__ void att1_body(
    int mb, int t, unsigned short* Ab, unsigned short* Bt, int* s_act,
    const float* __restrict__ clip, const float* __restrict__ wc,
    const float* __restrict__ bc, const int* __restrict__ mask,
    unsigned short* __restrict__ att)
{
    const int m0 = mb * 32;             // linear row = b*256 + l
    if (t < 32) s_act[t] = mask[m0 + t];
    __syncthreads();

    // phase 1: stage active rows (32 x 512 f32 -> bf16), two batched load groups
#pragma unroll
    for (int h = 0; h < 2; ++h) {
        float4 tmp[8];
#pragma unroll
        for (int k = 0; k < 8; ++k) {
            const int c = t + ((h * 8 + k) << 8), row = c >> 7, q = c & 127;
            if (s_act[row]) tmp[k] = *(const float4*)(clip + (size_t)(m0 + row) * 512 + q * 4);
        }
#pragma unroll
        for (int k = 0; k < 8; ++k) {
            const int c = t + ((h * 8 + k) << 8), row = c >> 7, q = c & 127;
            if (s_act[row]) *(uint2*)&Ab[row * AST + q * 4] = pack4(tmp[k]);
        }
    }

    const int w = t >> 6, lane = t & 63;
    const int col = lane & 15, hi = lane >> 4;
    f32x4 acc[2][2];
#pragma unroll
    for (int i = 0; i < 2; ++i)
#pragma unroll
        for (int j = 0; j < 2; ++j)
#pragma unroll
            for (int r = 0; r < 4; ++r) acc[i][j][r] = 0.f;

    for (int kt = 0; kt < 8; ++kt) {
        const int k0 = kt * 64;
        float4 tb[8];
#pragma unroll
        for (int k = 0; k < 8; ++k) {   // wc K-tile (L2-hot), issued before barrier
            const int c = t + (k << 8), row = c >> 4, q = c & 15;
            tb[k] = *(const float4*)(wc + (size_t)row * 512 + k0 + q * 4);
        }
        __syncthreads();   // prev tile's Bt reads done; (kt=0) phase-1 Ab visible
#pragma unroll
        for (int k = 0; k < 8; ++k) {
            const int c = t + (k << 8), row = c >> 4, q = c & 15;
            *(uint2*)&Bt[row * LST + q * 4] = pack4(tb[k]);
        }
        __syncthreads();
#pragma unroll
        for (int sub = 0; sub < 2; ++sub) {
            const int ko = sub * 32 + hi * 8;
            bf16x8 af[2], bfr[2];
            af[0] = *(const bf16x8*)&Ab[col * AST + k0 + ko];
            af[1] = *(const bf16x8*)&Ab[(16 + col) * AST + k0 + ko];
            bfr[0] = *(const bf16x8*)&Bt[(w * 32 + col) * LST + ko];
            bfr[1] = *(const bf16x8*)&Bt[(w * 32 + 16 + col) * LST + ko];
#pragma unroll
            for (int i = 0; i < 2; ++i)
#pragma unroll
                for (int j = 0; j < 2; ++j)
                    acc[i][j] = __builtin_amdgcn_mfma_f32_16x16x32_bf16(af[i], bfr[j], acc[i][j], 0, 0, 0);
        }
    }
#pragma unroll
    for (int i = 0; i < 2; ++i)
#pragma unroll
        for (int j = 0; j < 2; ++j) {
            const int n = w * 32 + j * 16 + col;
            const float bias = bc[n];
#pragma unroll
            for (int r = 0; r < 4; ++r) {
                const int m = i * 16 + hi * 4 + r;
                if (s_act[m])
                    att[(size_t)(m0 + m) * 128 + n] = f2b(acc[i][j][r] + bias);
            }
        }
}

// K1: blocks 0..255 = layer0 gemm+cell; blocks 256..3327 = att1 (mb 0..3071)
// LDS = 51.9 KB/block -> 3 blocks/CU (155.5 KB of 160 KB); (256,3) asks for them.
__global__ __launch_bounds__(256, 3)
void k1_fused(const float* xt, const float* video, const float* sh2, const float* sh0,
              const float* w_ih0, const float* w_hh0, const float* b_ih0, const float* b_hh0,
              const float* c_prev0, float* h_out0, float* c_out0,
              const float* clip, const float* wc, const float* bc,
              const int* mask, unsigned short* att)
{
    __shared__ unsigned short Ab[32 * AST];   // 33280 B (gate path uses first 64*72)
    __shared__ unsigned short Bt[128 * LST];  // 18432 B
    __shared__ int s_act[32];
    if (blockIdx.x < 256) {
        gate_body<256>(blockIdx.x, threadIdx.x, Ab, Bt,
                       xt, video, sh2, sh0, 512, 0, 512, 512,
                       w_ih0, w_ih0 + 512, w_ih0 + 1024, w_hh0, 1536, 1536, 1536, 512,
                       b_ih0, b_hh0, c_prev0, h_out0, c_out0, nullptr, 2048);
    } else {
        att1_body(blockIdx.x - 256, threadIdx.x, Ab, Bt, s_act, clip, wc, bc, mask, att);
    }
}

// K2: blocks 0..255 = layer1 gemm+cell (NT=256); blocks 256..1279 = att1 (mb 3072..4095)
// Fills K2's previously-idle machine (old K2 was 512x128 = 4 waves/CU) with the
// tail of att1; att is only consumed by K3, which launches after K2.
__global__ __launch_bounds__(256, 3)
void k2_fused(const float* event, const float* h0, const float* sh1,
              const float* w_ih1, const float* w_hh1, const float* b_ih1, const float* b_hh1,
              const float* c_prev1, float* h_out1, float* c_out1,
              const float* clip, const float* wc, const float* bc,
              const int* mask, unsigned short* att)
{
    __shared__ unsigned short Ab[32 * AST];
    __shared__ unsigned short Bt[128 * LST];
    __shared__ int s_act[32];
    if (blockIdx.x < 256) {
        gate_body<256>(blockIdx.x, threadIdx.x, Ab, Bt,
                       event, h0, sh1, nullptr, 512, 512, 512, 0,
                       w_ih1, w_ih1 + 512, w_hh1, nullptr, 1024, 1024, 512, 0,
                       b_ih1, b_hh1, c_prev1, h_out1, c_out1, nullptr, 1536);
    } else {
        att1_body(3072 + (int)blockIdx.x - 256, threadIdx.x, Ab, Bt, s_act, clip, wc, bc, mask, att);
    }
}

__global__ __launch_bounds__(128, 4)
void gate_layer(const float* A0, const float* A1, const float* A2,
                int as0, int as1, int as2,
                const float* w_ih, const float* w_hh,
                const float* b_ih, const float* b_hh,
                const float* c_prev, float* h_out, float* c_out, float* h_dup, int K)
{
    __shared__ unsigned short Al[32 * LST];
    __shared__ unsigned short Bl[64 * LST];
    gate_body<128>(blockIdx.x, threadIdx.x, Al, Bl,
                   A0, A1, A2, nullptr, as0, as1, as2, 0,
                   w_ih, w_ih + 512, w_hh, nullptr, 1024, 1024, 512, 0,
                   b_ih, b_hh, c_prev, h_out, c_out, h_dup, K);
}

// ---------------- att2: scores + masked softmax + weighted clip sum ----------------
__global__ __launch_bounds__(256)
void att2_kernel(const unsigned short* __restrict__ att, const float* __restrict__ h1,
                 const float* __restrict__ wh, const float* __restrict__ bh,
                 const float* __restrict__ wa, const float* __restrict__ ba,
                 const float* __restrict__ clip, const int* __restrict__ mask,
                 float* __restrict__ att_res)
{
    __shared__ float s_h1[512];
    __shared__ float s_atth[128];
    __shared__ float s_part[256];
    __shared__ float s_wa[128];
    __shared__ float s_sc[256];
    __shared__ float s_red[8];
    __shared__ float s_w[256];
    __shared__ int s_idx[256];
    __shared__ int s_cnt;
    const int b = blockIdx.x, t = threadIdx.x;
    if (t == 0) s_cnt = 0;
    const int act = mask[(size_t)b * 256 + t];

    s_h1[t]       = h1[(size_t)b * 512 + t];
    s_h1[256 + t] = h1[(size_t)b * 512 + 256 + t];
    if (t < 128) s_wa[t] = wa[t];
    __syncthreads();

    {   // att_h partials
        const int a = t & 127, half = t >> 7;
        const float4* wr4 = (const float4*)(wh + (size_t)a * 512 + half * 256);
        const float* hh = s_h1 + half * 256;
        float s = 0.f;
#pragma unroll 4
        for (int k4 = 0; k4 < 64; ++k4) {
            const float4 vv = wr4[k4];
            const float* hp = hh + k4 * 4;
            s += vv.x * hp[0] + vv.y * hp[1] + vv.z * hp[2] + vv.w * hp[3];
        }
        s_part[t] = s;
    }
    __syncthreads();
    if (t < 128) s_atth[t] = s_part[t] + s_part[128 + t] + bh[t];
    __syncthreads();

    {   // score for l = t (garbage for inactive t -- masked below)
        const uint4* ar4 = (const uint4*)(att + ((size_t)b * 256 + t) * 128);
        float s = ba[0];
#pragma unroll 4
        for (int k8 = 0; k8 < 16; ++k8) {
            const uint4 vv = ar4[k8];
            float v0, v1, v2, v3, v4, v5, v6, v7;
            unpack2(vv.x, v0, v1); unpack2(vv.y, v2, v3);
            unpack2(vv.z, v4, v5); unpack2(vv.w, v6, v7);
            const int a0 = k8 * 8;
            s += s_wa[a0 + 0] * tanhfast(v0 + s_atth[a0 + 0]);
            s += s_wa[a0 + 1] * tanhfast(v1 + s_atth[a0 + 1]);
            s += s_wa[a0 + 2] * tanhfast(v2 + s_atth[a0 + 2]);
            s += s_wa[a0 + 3] * tanhfast(v3 + s_atth[a0 + 3]);
            s += s_wa[a0 + 4] * tanhfast(v4 + s_atth[a0 + 4]);
            s += s_wa[a0 + 5] * tanhfast(v5 + s_atth[a0 + 5]);
            s += s_wa[a0 + 6] * tanhfast(v6 + s_atth[a0 + 6]);
            s += s_wa[a0 + 7] * tanhfast(v7 + s_atth[a0 + 7]);
        }
        s_sc[t] = s;
    }
    __syncthreads();

    float v = act ? s_sc[t] : -3.4e38f;   // mask BEFORE max (garbage rows)
    for (int off = 32; off > 0; off >>= 1) v = fmaxf(v, __shfl_down(v, off));
    if ((t & 63) == 0) s_red[t >> 6] = v;
    __syncthreads();
    if (t == 0) s_red[4] = fmaxf(fmaxf(s_red[0], s_red[1]), fmaxf(s_red[2], s_red[3]));
    __syncthreads();
    const float mx = s_red[4];
    const float e = act ? __expf(s_sc[t] - mx) : 0.f;
    float sv = e;
    for (int off = 32; off > 0; off >>= 1) sv += __shfl_down(sv, off);
    if ((t & 63) == 0) s_red[t >> 6] = sv;
    __syncthreads();
    if (t == 0) s_red[5] = s_red[0] + s_red[1] + s_red[2] + s_red[3];
    __syncthreads();
    const float wgt = e / s_red[5];
    if (wgt != 0.f) {   // compact active l's (sum is order-free)
        const int pos = atomicAdd(&s_cnt, 1);
        s_idx[pos] = t;
        s_w[pos] = wgt;
    }
    __syncthreads();
    const int cnt = s_cnt;

    float a0 = 0.f, a1 = 0.f;
    const float* cb = clip + (size_t)b * (256 * 512);
    int i = 0;
    for (; i + 8 <= cnt; i += 8) {
        float2 vv[8]; float ww[8];
#pragma unroll
        for (int u = 0; u < 8; ++u) {
            vv[u] = *(const float2*)&cb[s_idx[i + u] * 512 + 2 * t];
            ww[u] = s_w[i + u];
        }
#pragma unroll
        for (int u = 0; u < 8; ++u) { a0 += ww[u] * vv[u].x; a1 += ww[u] * vv[u].y; }
    }
    for (; i < cnt; ++i) {
        const float2 vv = *(const float2*)&cb[s_idx[i] * 512 + 2 * t];
        a0 += s_w[i] * vv.x;
        a1 += s_w[i] * vv.y;
    }
    float2 o; o.x = a0; o.y = a1;
    *(float2*)&att_res[(size_t)b * 512 + 2 * t] = o;
}

extern "C" void kernel_launch(void* const* d_in, const int* in_sizes, int n_in,
                              void* d_out, int out_size, void* d_ws, size_t ws_size,
                              hipStream_t stream) {
    typedef const float* cf;
    cf xt      = (cf)d_in[0];
    cf video   = (cf)d_in[1];
    cf event   = (cf)d_in[2];
    cf clip    = (cf)d_in[3];
    const int* mask = (const int*)d_in[4];
    cf state_h = (cf)d_in[5];
    cf state_c = (cf)d_in[6];
    cf w_ih0 = (cf)d_in[7],  w_hh0 = (cf)d_in[8],  b_ih0 = (cf)d_in[9],  b_hh0 = (cf)d_in[10];
    cf w_ih1 = (cf)d_in[11], w_hh1 = (cf)d_in[12], b_ih1 = (cf)d_in[13], b_hh1 = (cf)d_in[14];
    cf w_ih2 = (cf)d_in[15], w_hh2 = (cf)d_in[16], b_ih2 = (cf)d_in[17], b_hh2 = (cf)d_in[18];
    cf wc = (cf)d_in[19], bc = (cf)d_in[20];
    cf wh = (cf)d_in[21], bh = (cf)d_in[22];
    cf wa = (cf)d_in[23], ba = (cf)d_in[24];

    float* out = (float*)d_out;
    const int BH = 512 * 512;
    float* new_h = out + BH;       // [3,B,H]
    float* new_c = out + 4 * BH;   // [3,B,H]

    unsigned short* att = (unsigned short*)d_ws;                // 32 MB bf16
    float* att_res      = (float*)((char*)d_ws + (32u << 20));  // 1 MB

    // K1: layer0 (gemm+cell, blocks 0-255) || att1 mb 0..3071 (blocks 256-3327)
    k1_fused<<<3328, 256, 0, stream>>>(
        xt, video, state_h + 2 * BH, state_h,
        w_ih0, w_hh0, b_ih0, b_hh0,
        state_c, new_h, new_c,
        clip, wc, bc, mask, att);

    // K2: layer1 gemm+cell (blocks 0-255) || att1 mb 3072..4095 (blocks 256-1279)
    k2_fused<<<1280, 256, 0, stream>>>(
        event, new_h, state_h + BH,
        w_ih1, w_hh1, b_ih1, b_hh1,
        state_c + BH, new_h + BH, new_c + BH,
        clip, wc, bc, mask, att);

    // K3: attention stage 2 (needs h1 + att)
    att2_kernel<<<512, 256, 0, stream>>>(att, new_h + BH, wh, bh, wa, ba, clip, mask, att_res);

    // K4: layer2 gemm+cell (A = [att_res | h1 | sh2]); h2 dual-written to out[0:BH]
    gate_layer<<<512, 128, 0, stream>>>(
        att_res, new_h + BH, state_h + 2 * BH, 512, 512, 512,
        w_ih2, w_hh2, b_ih2, b_hh2,
        state_c + 2 * BH, new_h + 2 * BH, new_c + 2 * BH, out, 1536);
}

// Round 4
// 567.735 us; speedup vs baseline: 1.2824x; 1.1713x over previous
//
#include <hip/hip_runtime.h>
#include <math.h>

typedef __attribute__((ext_vector_type(8))) short bf16x8;  // 8 bf16 = 4 VGPR
typedef __attribute__((ext_vector_type(4))) float f32x4;   // MFMA acc

constexpr int LST = 72;    // B-tile LDS row stride (shorts): 144 B
constexpr int AST = 520;   // att1 A-tile LDS row stride (shorts): 1040 B (bank step 4 -> 2-way max)

__device__ __forceinline__ unsigned short f2b(float f) {
    union { float f; unsigned int i; } c; c.f = f;
    unsigned int i = c.i;
    return (unsigned short)((i + 0x7fffu + ((i >> 16) & 1u)) >> 16);  // RNE
}
__device__ __forceinline__ void unpack2(unsigned int v, float& lo, float& hi) {
    union { unsigned int i; float f; } c0, c1;
    c0.i = v << 16; c1.i = v & 0xffff0000u;
    lo = c0.f; hi = c1.f;
}
__device__ __forceinline__ uint2 pack4(float4 v) {
    uint2 pk;
    pk.x = (unsigned int)f2b(v.x) | ((unsigned int)f2b(v.y) << 16);
    pk.y = (unsigned int)f2b(v.z) | ((unsigned int)f2b(v.w) << 16);
    return pk;
}
__device__ __forceinline__ float sigf(float x) { return 1.f / (1.f + __expf(-x)); }
__device__ __forceinline__ float tanhfast(float x) { return 1.f - 2.f / (1.f + __expf(2.f * x)); }

// ---------------- K0: one-shot f32 -> bf16 prepack of all constant GEMM operands ----------
// Segment layout (element offsets, all multiples of 512 so 8-elem groups never straddle):
//   wb0    [0,        3145728)  w_ih0  (2048x1536)
//   wbh0   [3145728,  4194304)  w_hh0  (2048x512)
//   wb1    [4194304,  6291456)  w_ih1  (2048x1024)
//   wbh1   [6291456,  7340032)  w_hh1  (2048x512)
//   wb2    [7340032,  9437184)  w_ih2  (2048x1024)   <-- full 2097152 (round-3 bug fixed)
//   wbh2   [9437184, 10485760)  w_hh2  (2048x512)
//   wcb    [10485760,10551296)  wc     (128x512)
//   xtb    [10551296,10813440)  xt     (512x512)
//   videob [10813440,10813952)  video  (512)
//   sh0b   [10813952,11076096)  state_h[0]
//   sh1b   [11076096,11338240)  state_h[1]
//   sh2b   [11338240,11600384)  state_h[2]
//   evb    [11600384,11862528)  event  (512x512)
__global__ __launch_bounds__(256)
void prepack_kernel(const float* __restrict__ w_ih0, const float* __restrict__ w_hh0,
                    const float* __restrict__ w_ih1, const float* __restrict__ w_hh1,
                    const float* __restrict__ w_ih2, const float* __restrict__ w_hh2,
                    const float* __restrict__ wc, const float* __restrict__ xt,
                    const float* __restrict__ video, const float* __restrict__ state_h,
                    const float* __restrict__ event, unsigned short* __restrict__ dst)
{
    const size_t NV = 11862528 / 8;   // total prepacked elems / 8 per thread-step
    for (size_t g = (size_t)blockIdx.x * 256 + threadIdx.x; g < NV;
         g += (size_t)gridDim.x * 256) {
        const size_t e = g * 8;
        const float* s; size_t o;
        if      (e < 3145728)  { s = w_ih0;            o = e; }
        else if (e < 4194304)  { s = w_hh0;            o = e - 3145728; }
        else if (e < 6291456)  { s = w_ih1;            o = e - 4194304; }
        else if (e < 7340032)  { s = w_hh1;            o = e - 6291456; }
        else if (e < 9437184)  { s = w_ih2;            o = e - 7340032; }
        else if (e < 10485760) { s = w_hh2;            o = e - 9437184; }
        else if (e < 10551296) { s = wc;               o = e - 10485760; }
        else if (e < 10813440) { s = xt;               o = e - 10551296; }
        else if (e < 10813952) { s = video;            o = e - 10813440; }
        else if (e < 11076096) { s = state_h;          o = e - 10813952; }  // sh0
        else if (e < 11338240) { s = state_h + 262144; o = e - 11076096; }  // sh1
        else if (e < 11600384) { s = state_h + 524288; o = e - 11338240; }  // sh2
        else                   { s = event;            o = e - 11600384; }
        const float4 a = *(const float4*)(s + o);
        const float4 b = *(const float4*)(s + o + 4);
        const uint2 p0 = pack4(a), p1 = pack4(b);
        uint4 ov; ov.x = p0.x; ov.y = p0.y; ov.z = p1.x; ov.w = p1.y;
        *(uint4*)(dst + e) = ov;
    }
}

// ---------------- gate GEMM + fused LSTM cell (bf16 prepacked A/B) ----------------
// gates = [A-pieces]@[W-pieces]^T + b_ih + b_hh, gate-interleaved N-mapping:
// block covers j0..j0+16 for all 4 gates; lane holds (i,f,g,o) of same (b,j).
template<int NT>
__device__ __forceinline__ void gate_body(
    int bx, int t, unsigned short* Al, unsigned short* Bl,
    const unsigned short* __restrict__ A0, const unsigned short* __restrict__ A1,
    const unsigned short* __restrict__ A2, const unsigned short* __restrict__ A3,
    int as0, int as1, int as2, int as3,
    const unsigned short* __restrict__ B0, const unsigned short* __restrict__ B1,
    const unsigned short* __restrict__ B2, const unsigned short* __restrict__ B3,
    int bs0, int bs1, int bs2, int bs3,
    const float* __restrict__ b_ih, const float* __restrict__ b_hh,
    const float* __restrict__ c_prev, float* __restrict__ h_out,
    float* __restrict__ c_out, float* __restrict__ h_dup,
    unsigned short* __restrict__ hb_out, int K)
{
    constexpr int BM = NT / 4;          // rows per block
    constexpr int MBLK = 512 / BM;
    constexpr int NA = BM * 16 / NT;    // A uint2-chunks per thread
    constexpr int NB = 1024 / NT;       // B uint2-chunks per thread
    const int mb = bx % MBLK, jb = bx / MBLK;
    const int m0 = mb * BM, j0 = jb * 16;
    const int w = t >> 6, lane = t & 63;
    const int col = lane & 15, hi = lane >> 4;

    f32x4 acc[4];
#pragma unroll
    for (int g = 0; g < 4; ++g)
#pragma unroll
        for (int r = 0; r < 4; ++r) acc[g][r] = 0.f;

    for (int kt = 0; kt < K; kt += 64) {
        const int p = kt >> 9, kin = kt & 511;
        const unsigned short* ap = (p == 0) ? A0 : (p == 1) ? A1 : (p == 2) ? A2 : A3;
        const int astr           = (p == 0) ? as0 : (p == 1) ? as1 : (p == 2) ? as2 : as3;
        const unsigned short* bp = (p == 0) ? B0 : (p == 1) ? B1 : (p == 2) ? B2 : B3;
        const int bstr           = (p == 0) ? bs0 : (p == 1) ? bs1 : (p == 2) ? bs2 : bs3;
        uint2 ta[NA], tb[NB];
#pragma unroll
        for (int k = 0; k < NA; ++k) {
            const int c = t + k * NT, row = c >> 4, q = c & 15;
            ta[k] = *(const uint2*)(ap + (astr ? (size_t)(m0 + row) * astr : 0) + kin + q * 4);
        }
#pragma unroll
        for (int k = 0; k < NB; ++k) {
            const int c = t + k * NT, row = c >> 4, q = c & 15;
            const int brow = (row >> 4) * 512 + j0 + (row & 15);
            tb[k] = *(const uint2*)(bp + (size_t)brow * bstr + kin + q * 4);
        }
        __syncthreads();   // previous tile's LDS reads done
#pragma unroll
        for (int k = 0; k < NA; ++k) {
            const int c = t + k * NT, row = c >> 4, q = c & 15;
            *(uint2*)&Al[row * LST + q * 4] = ta[k];
        }
#pragma unroll
        for (int k = 0; k < NB; ++k) {
            const int c = t + k * NT, row = c >> 4, q = c & 15;
            *(uint2*)&Bl[row * LST + q * 4] = tb[k];
        }
        __syncthreads();
#pragma unroll
        for (int sub = 0; sub < 2; ++sub) {
            const int ko = sub * 32 + hi * 8;
            const bf16x8 af = *(const bf16x8*)&Al[(w * 16 + col) * LST + ko];
#pragma unroll
            for (int g = 0; g < 4; ++g) {
                const bf16x8 bfr = *(const bf16x8*)&Bl[(g * 16 + col) * LST + ko];
                acc[g] = __builtin_amdgcn_mfma_f32_16x16x32_bf16(af, bfr, acc[g], 0, 0, 0);
            }
        }
    }
    // epilogue: LSTM cell per lane
    const int j = j0 + col;
    const float bi = b_ih[j]        + b_hh[j];
    const float bf = b_ih[512 + j]  + b_hh[512 + j];
    const float bg = b_ih[1024 + j] + b_hh[1024 + j];
    const float bo = b_ih[1536 + j] + b_hh[1536 + j];
#pragma unroll
    for (int r = 0; r < 4; ++r) {
        const int bidx = m0 + w * 16 + hi * 4 + r;
        const size_t off = (size_t)bidx * 512 + j;
        const float gi = acc[0][r] + bi, gf = acc[1][r] + bf;
        const float gg = acc[2][r] + bg, go = acc[3][r] + bo;
        const float c = c_prev[off];
        const float cn = sigf(gf) * c + sigf(gi) * tanhfast(gg);
        const float hn = sigf(go) * tanhfast(cn);
        h_out[off] = hn;
        c_out[off] = cn;
        if (h_dup) h_dup[off] = hn;
        if (hb_out) hb_out[off] = f2b(hn);   // bf16 shadow for next layer's A staging
    }
}

// ---------------- att1: 32-row block, whole-K LDS-resident A, mask-skip ----------------
// B (wc) prepacked bf16: Bt staging is a plain uint2 copy (no f2b VALU).
__device__ __forceinline__ void att1_body(
    int mb, int t, unsigned short* Ab, unsigned short* Bt, int* s_act,
    const float* __restrict__ clip, const unsigned short* __restrict__ wcb,
    const float* __restrict__ bc, const int* __restrict__ mask,
    unsigned short* __restrict__ att)
{
    const int m0 = mb * 32;             // linear row = b*256 + l
    if (t < 32) s_act[t] = mask[m0 + t];
    __syncthreads();

    // phase 1: stage active rows (32 x 512 f32 -> bf16), two batched load groups
#pragma unroll
    for (int h = 0; h < 2; ++h) {
        float4 tmp[8];
#pragma unroll
        for (int k = 0; k < 8; ++k) {
            const int c = t + ((h * 8 + k) << 8), row = c >> 7, q = c & 127;
            if (s_act[row]) tmp[k] = *(const float4*)(clip + (size_t)(m0 + row) * 512 + q * 4);
        }
#pragma unroll
        for (int k = 0; k < 8; ++k) {
            const int c = t + ((h * 8 + k) << 8), row = c >> 7, q = c & 127;
            if (s_act[row]) *(uint2*)&Ab[row * AST + q * 4] = pack4(tmp[k]);
        }
    }

    const int w = t >> 6, lane = t & 63;
    const int col = lane & 15, hi = lane >> 4;
    f32x4 acc[2][2];
#pragma unroll
    for (int i = 0; i < 2; ++i)
#pragma unroll
        for (int j = 0; j < 2; ++j)
#pragma unroll
            for (int r = 0; r < 4; ++r) acc[i][j][r] = 0.f;

    for (int kt = 0; kt < 8; ++kt) {
        const int k0 = kt * 64;
        uint2 tb[8];
#pragma unroll
        for (int k = 0; k < 8; ++k) {   // wcb K-tile (bf16, L2-hot), issued before barrier
            const int c = t + (k << 8), row = c >> 4, q = c & 15;
            tb[k] = *(const uint2*)(wcb + (size_t)row * 512 + k0 + q * 4);
        }
        __syncthreads();   // prev tile's Bt reads done; (kt=0) phase-1 Ab visible
#pragma unroll
        for (int k = 0; k < 8; ++k) {
            const int c = t + (k << 8), row = c >> 4, q = c & 15;
            *(uint2*)&Bt[row * LST + q * 4] = tb[k];
        }
        __syncthreads();
#pragma unroll
        for (int sub = 0; sub < 2; ++sub) {
            const int ko = sub * 32 + hi * 8;
            bf16x8 af[2], bfr[2];
            af[0] = *(const bf16x8*)&Ab[col * AST + k0 + ko];
            af[1] = *(const bf16x8*)&Ab[(16 + col) * AST + k0 + ko];
            bfr[0] = *(const bf16x8*)&Bt[(w * 32 + col) * LST + ko];
            bfr[1] = *(const bf16x8*)&Bt[(w * 32 + 16 + col) * LST + ko];
#pragma unroll
            for (int i = 0; i < 2; ++i)
#pragma unroll
                for (int j = 0; j < 2; ++j)
                    acc[i][j] = __builtin_amdgcn_mfma_f32_16x16x32_bf16(af[i], bfr[j], acc[i][j], 0, 0, 0);
        }
    }
#pragma unroll
    for (int i = 0; i < 2; ++i)
#pragma unroll
        for (int j = 0; j < 2; ++j) {
            const int n = w * 32 + j * 16 + col;
            const float bias = bc[n];
#pragma unroll
            for (int r = 0; r < 4; ++r) {
                const int m = i * 16 + hi * 4 + r;
                if (s_act[m])
                    att[(size_t)(m0 + m) * 128 + n] = f2b(acc[i][j][r] + bias);
            }
        }
}

// K1: blocks 0..255 = layer0 gemm+cell; blocks 256..3327 = att1 (mb 0..3071)
// LDS = 51.9 KB/block -> 3 blocks/CU (155.5 KB of 160 KB); (256,3) asks for them.
__global__ __launch_bounds__(256, 3)
void k1_fused(const unsigned short* xtb, const unsigned short* videob,
              const unsigned short* sh2b, const unsigned short* sh0b,
              const unsigned short* wb0, const unsigned short* wbh0,
              const float* b_ih0, const float* b_hh0,
              const float* c_prev0, float* h_out0, float* c_out0, unsigned short* h0b,
              const float* clip, const unsigned short* wcb, const float* bc,
              const int* mask, unsigned short* att)
{
    __shared__ unsigned short Ab[32 * AST];   // 33280 B (gate path uses first 64*72)
    __shared__ unsigned short Bt[128 * LST];  // 18432 B
    __shared__ int s_act[32];
    if (blockIdx.x < 256) {
        gate_body<256>(blockIdx.x, threadIdx.x, Ab, Bt,
                       xtb, videob, sh2b, sh0b, 512, 0, 512, 512,
                       wb0, wb0 + 512, wb0 + 1024, wbh0, 1536, 1536, 1536, 512,
                       b_ih0, b_hh0, c_prev0, h_out0, c_out0, nullptr, h0b, 2048);
    } else {
        att1_body(blockIdx.x - 256, threadIdx.x, Ab, Bt, s_act, clip, wcb, bc, mask, att);
    }
}

// K2: blocks 0..255 = layer1 gemm+cell (NT=256); blocks 256..1279 = att1 (mb 3072..4095)
__global__ __launch_bounds__(256, 3)
void k2_fused(const unsigned short* evb, const unsigned short* h0b, const unsigned short* sh1b,
              const unsigned short* wb1, const unsigned short* wbh1,
              const float* b_ih1, const float* b_hh1,
              const float* c_prev1, float* h_out1, float* c_out1, unsigned short* h1b,
              const float* clip, const unsigned short* wcb, const float* bc,
              const int* mask, unsigned short* att)
{
    __shared__ unsigned short Ab[32 * AST];
    __shared__ unsigned short Bt[128 * LST];
    __shared__ int s_act[32];
    if (blockIdx.x < 256) {
        gate_body<256>(blockIdx.x, threadIdx.x, Ab, Bt,
                       evb, h0b, sh1b, nullptr, 512, 512, 512, 0,
                       wb1, wb1 + 512, wbh1, nullptr, 1024, 1024, 512, 0,
                       b_ih1, b_hh1, c_prev1, h_out1, c_out1, nullptr, h1b, 1536);
    } else {
        att1_body(3072 + (int)blockIdx.x - 256, threadIdx.x, Ab, Bt, s_act, clip, wcb, bc, mask, att);
    }
}

__global__ __launch_bounds__(128, 4)
void gate_layer(const unsigned short* A0, const unsigned short* A1, const unsigned short* A2,
                int as0, int as1, int as2,
                const unsigned short* wb, const unsigned short* wbh,
                const float* b_ih, const float* b_hh,
                const float* c_prev, float* h_out, float* c_out, float* h_dup, int K)
{
    __shared__ unsigned short Al[32 * LST];
    __shared__ unsigned short Bl[64 * LST];
    gate_body<128>(blockIdx.x, threadIdx.x, Al, Bl,
                   A0, A1, A2, nullptr, as0, as1, as2, 0,
                   wb, wb + 512, wbh, nullptr, 1024, 1024, 512, 0,
                   b_ih, b_hh, c_prev, h_out, c_out, h_dup, nullptr, K);
}

// ---------------- att2: scores + masked softmax + weighted clip sum ----------------
__global__ __launch_bounds__(256)
void att2_kernel(const unsigned short* __restrict__ att, const float* __restrict__ h1,
                 const float* __restrict__ wh, const float* __restrict__ bh,
                 const float* __restrict__ wa, const float* __restrict__ ba,
                 const float* __restrict__ clip, const int* __restrict__ mask,
                 unsigned short* __restrict__ att_res_b)
{
    __shared__ float s_h1[512];
    __shared__ float s_atth[128];
    __shared__ float s_part[256];
    __shared__ float s_wa[128];
    __shared__ float s_sc[256];
    __shared__ float s_red[8];
    __shared__ float s_w[256];
    __shared__ int s_idx[256];
    __shared__ int s_cnt;
    const int b = blockIdx.x, t = threadIdx.x;
    if (t == 0) s_cnt = 0;
    const int act = mask[(size_t)b * 256 + t];

    s_h1[t]       = h1[(size_t)b * 512 + t];
    s_h1[256 + t] = h1[(size_t)b * 512 + 256 + t];
    if (t < 128) s_wa[t] = wa[t];
    __syncthreads();

    {   // att_h partials
        const int a = t & 127, half = t >> 7;
        const float4* wr4 = (const float4*)(wh + (size_t)a * 512 + half * 256);
        const float* hh = s_h1 + half * 256;
        float s = 0.f;
#pragma unroll 4
        for (int k4 = 0; k4 < 64; ++k4) {
            const float4 vv = wr4[k4];
            const float* hp = hh + k4 * 4;
            s += vv.x * hp[0] + vv.y * hp[1] + vv.z * hp[2] + vv.w * hp[3];
        }
        s_part[t] = s;
    }
    __syncthreads();
    if (t < 128) s_atth[t] = s_part[t] + s_part[128 + t] + bh[t];
    __syncthreads();

    {   // score for l = t (garbage for inactive t -- masked below)
        const uint4* ar4 = (const uint4*)(att + ((size_t)b * 256 + t) * 128);
        float s = ba[0];
#pragma unroll 4
        for (int k8 = 0; k8 < 16; ++k8) {
            const uint4 vv = ar4[k8];
            float v0, v1, v2, v3, v4, v5, v6, v7;
            unpack2(vv.x, v0, v1); unpack2(vv.y, v2, v3);
            unpack2(vv.z, v4, v5); unpack2(vv.w, v6, v7);
            const int a0 = k8 * 8;
            s += s_wa[a0 + 0] * tanhfast(v0 + s_atth[a0 + 0]);
            s += s_wa[a0 + 1] * tanhfast(v1 + s_atth[a0 + 1]);
            s += s_wa[a0 + 2] * tanhfast(v2 + s_atth[a0 + 2]);
            s += s_wa[a0 + 3] * tanhfast(v3 + s_atth[a0 + 3]);
            s += s_wa[a0 + 4] * tanhfast(v4 + s_atth[a0 + 4]);
            s += s_wa[a0 + 5] * tanhfast(v5 + s_atth[a0 + 5]);
            s += s_wa[a0 + 6] * tanhfast(v6 + s_atth[a0 + 6]);
            s += s_wa[a0 + 7] * tanhfast(v7 + s_atth[a0 + 7]);
        }
        s_sc[t] = s;
    }
    __syncthreads();

    float v = act ? s_sc[t] : -3.4e38f;   // mask BEFORE max (garbage rows)
    for (int off = 32; off > 0; off >>= 1) v = fmaxf(v, __shfl_down(v, off));
    if ((t & 63) == 0) s_red[t >> 6] = v;
    __syncthreads();
    if (t == 0) s_red[4] = fmaxf(fmaxf(s_red[0], s_red[1]), fmaxf(s_red[2], s_red[3]));
    __syncthreads();
    const float mx = s_red[4];
    const float e = act ? __expf(s_sc[t] - mx) : 0.f;
    float sv = e;
    for (int off = 32; off > 0; off >>= 1) sv += __shfl_down(sv, off);
    if ((t & 63) == 0) s_red[t >> 6] = sv;
    __syncthreads();
    if (t == 0) s_red[5] = s_red[0] + s_red[1] + s_red[2] + s_red[3];
    __syncthreads();
    const float wgt = e / s_red[5];
    if (wgt != 0.f) {   // compact active l's (sum is order-free)
        const int pos = atomicAdd(&s_cnt, 1);
        s_idx[pos] = t;
        s_w[pos] = wgt;
    }
    __syncthreads();
    const int cnt = s_cnt;

    float a0 = 0.f, a1 = 0.f;
    const float* cb = clip + (size_t)b * (256 * 512);
    int i = 0;
    for (; i + 8 <= cnt; i += 8) {
        float2 vv[8]; float ww[8];
#pragma unroll
        for (int u = 0; u < 8; ++u) {
            vv[u] = *(const float2*)&cb[s_idx[i + u] * 512 + 2 * t];
            ww[u] = s_w[i + u];
        }
#pragma unroll
        for (int u = 0; u < 8; ++u) { a0 += ww[u] * vv[u].x; a1 += ww[u] * vv[u].y; }
    }
    for (; i < cnt; ++i) {
        const float2 vv = *(const float2*)&cb[s_idx[i] * 512 + 2 * t];
        a0 += s_w[i] * vv.x;
        a1 += s_w[i] * vv.y;
    }
    // att_res written directly as bf16 (only consumer is K4's bf16 A-staging)
    const unsigned int ov = (unsigned int)f2b(a0) | ((unsigned int)f2b(a1) << 16);
    *(unsigned int*)&att_res_b[(size_t)b * 512 + 2 * t] = ov;
}

extern "C" void kernel_launch(void* const* d_in, const int* in_sizes, int n_in,
                              void* d_out, int out_size, void* d_ws, size_t ws_size,
                              hipStream_t stream) {
    typedef const float* cf;
    cf xt      = (cf)d_in[0];
    cf video   = (cf)d_in[1];
    cf event   = (cf)d_in[2];
    cf clip    = (cf)d_in[3];
    const int* mask = (const int*)d_in[4];
    cf state_h = (cf)d_in[5];
    cf state_c = (cf)d_in[6];
    cf w_ih0 = (cf)d_in[7],  w_hh0 = (cf)d_in[8],  b_ih0 = (cf)d_in[9],  b_hh0 = (cf)d_in[10];
    cf w_ih1 = (cf)d_in[11], w_hh1 = (cf)d_in[12], b_ih1 = (cf)d_in[13], b_hh1 = (cf)d_in[14];
    cf w_ih2 = (cf)d_in[15], w_hh2 = (cf)d_in[16], b_ih2 = (cf)d_in[17], b_hh2 = (cf)d_in[18];
    cf wc = (cf)d_in[19], bc = (cf)d_in[20];
    cf wh = (cf)d_in[21], bh = (cf)d_in[22];
    cf wa = (cf)d_in[23], ba = (cf)d_in[24];

    float* out = (float*)d_out;
    const int BH = 512 * 512;
    float* new_h = out + BH;       // [3,B,H]
    float* new_c = out + 4 * BH;   // [3,B,H]

    unsigned short* att = (unsigned short*)d_ws;                       // 32 MB bf16
    unsigned short* pp  = (unsigned short*)((char*)d_ws + (32u << 20));// prepack base
    // prepack segment offsets (shorts) -- must match prepack_kernel layout
    unsigned short* wb0    = pp + 0;
    unsigned short* wbh0   = pp + 3145728;
    unsigned short* wb1    = pp + 4194304;
    unsigned short* wbh1   = pp + 6291456;
    unsigned short* wb2    = pp + 7340032;
    unsigned short* wbh2   = pp + 9437184;
    unsigned short* wcb    = pp + 10485760;
    unsigned short* xtb    = pp + 10551296;
    unsigned short* videob = pp + 10813440;
    unsigned short* sh0b   = pp + 10813952;
    unsigned short* sh1b   = pp + 11076096;
    unsigned short* sh2b   = pp + 11338240;
    unsigned short* evb    = pp + 11600384;
    // runtime bf16 shadows (written by K1/K2/K3)
    unsigned short* h0b    = pp + 11862528;
    unsigned short* h1b    = pp + 12124672;
    unsigned short* arb    = pp + 12386816;   // att_res bf16

    // K0: prepack all constant operands to bf16 (~70 MB traffic, ~12 us)
    prepack_kernel<<<2048, 256, 0, stream>>>(
        w_ih0, w_hh0, w_ih1, w_hh1, w_ih2, w_hh2, wc,
        xt, video, state_h, event, pp);

    // K1: layer0 (gemm+cell, blocks 0-255) || att1 mb 0..3071 (blocks 256-3327)
    k1_fused<<<3328, 256, 0, stream>>>(
        xtb, videob, sh2b, sh0b,
        wb0, wbh0, b_ih0, b_hh0,
        state_c, new_h, new_c, h0b,
        clip, wcb, bc, mask, att);

    // K2: layer1 gemm+cell (blocks 0-255) || att1 mb 3072..4095 (blocks 256-1279)
    k2_fused<<<1280, 256, 0, stream>>>(
        evb, h0b, sh1b,
        wb1, wbh1, b_ih1, b_hh1,
        state_c + BH, new_h + BH, new_c + BH, h1b,
        clip, wcb, bc, mask, att);

    // K3: attention stage 2 (needs h1 + att); att_res written as bf16
    att2_kernel<<<512, 256, 0, stream>>>(att, new_h + BH, wh, bh, wa, ba, clip, mask, arb);

    // K4: layer2 gemm+cell (A = [att_res_b | h1b | sh2b]); h2 dual-written to out[0:BH]
    gate_layer<<<512, 128, 0, stream>>>(
        arb, h1b, sh2b, 512, 512, 512,
        wb2, wbh2, b_ih2, b_hh2,
        state_c + 2 * BH, new_h + 2 * BH, new_c + 2 * BH, out, 1536);
}